// Round 5
// baseline (7267.403 us; speedup 1.0000x reference)
//
#include <hip/hip_runtime.h>
#include <math.h>

#define BATCH 4096
#define NPART 100
#define PSZ   64

__device__ __forceinline__ void fma4(float4& d, const float s, const float4 v) {
    d.x = fmaf(s, v.x, d.x); d.y = fmaf(s, v.y, d.y);
    d.z = fmaf(s, v.z, d.z); d.w = fmaf(s, v.w, d.w);
}
__device__ __forceinline__ float4 addrelu4(const float4 a, const float4 b) {
    return make_float4(fmaxf(a.x + b.x, 0.f), fmaxf(a.y + b.y, 0.f),
                       fmaxf(a.z + b.z, 0.f), fmaxf(a.w + b.w, 0.f));
}

// ------------------------------------------------------------------
// Encoder chunk worker, v5 tile: lane = (rg in 0..3, cg in 0..15),
// 8 rows (rg+4j) x 4 cols (col0..col0+3). Per k0 iter: 4 W-loads
// (halved vs v4) + 8 A-loads per 128 FMAs. W1/W2 streamed from global
// (one read per chunk per block, L2-hot). h1 stride 260 -> bank-balanced.
// ------------------------------------------------------------------
template<int NJ>
__device__ __forceinline__ void enc_chunk(
    const float* __restrict__ xb, const int rbase,
    const float* __restrict__ w1c, const float* __restrict__ w2c,
    float* __restrict__ h1s, const int rg, const int col0,
    const float4 b1v, const float4 b2v, float4& msum)
{
    // ---- fc1: h1 = relu(x @ W1 + b1), K=64
    float4 acc1[NJ];
    #pragma unroll
    for (int j = 0; j < NJ; ++j) acc1[j] = make_float4(0.f, 0.f, 0.f, 0.f);
    #pragma unroll 2
    for (int k0 = 0; k0 < 64; k0 += 4) {
        float4 w[4];
        #pragma unroll
        for (int kk = 0; kk < 4; ++kk)
            w[kk] = *(const float4*)(w1c + (k0 + kk) * 256);
        #pragma unroll
        for (int j = 0; j < NJ; ++j) {
            const float4 a = *(const float4*)(xb + (size_t)(rbase + rg + 4 * j) * 64 + k0);
            fma4(acc1[j], a.x, w[0]); fma4(acc1[j], a.y, w[1]);
            fma4(acc1[j], a.z, w[2]); fma4(acc1[j], a.w, w[3]);
        }
    }
    #pragma unroll
    for (int j = 0; j < NJ; ++j)
        *(float4*)&h1s[(rg + 4 * j) * 260 + col0] = addrelu4(acc1[j], b1v);
    __syncthreads();

    // ---- fc2: K=256, A from LDS (broadcast, conflict-free), B from global
    float4 acc2[NJ];
    #pragma unroll
    for (int j = 0; j < NJ; ++j) acc2[j] = make_float4(0.f, 0.f, 0.f, 0.f);
    #pragma unroll 2
    for (int k0 = 0; k0 < 256; k0 += 4) {
        float4 w[4];
        #pragma unroll
        for (int kk = 0; kk < 4; ++kk)
            w[kk] = *(const float4*)(w2c + (k0 + kk) * 256);
        #pragma unroll
        for (int j = 0; j < NJ; ++j) {
            const float4 a = *(const float4*)&h1s[(rg + 4 * j) * 260 + k0];
            fma4(acc2[j], a.x, w[0]); fma4(acc2[j], a.y, w[1]);
            fma4(acc2[j], a.z, w[2]); fma4(acc2[j], a.w, w[3]);
        }
    }
    #pragma unroll
    for (int j = 0; j < NJ; ++j) {
        const float4 r = addrelu4(acc2[j], b2v);
        msum.x += r.x; msum.y += r.y; msum.z += r.z; msum.w += r.w;
    }
    __syncthreads();   // protect h1 for next chunk
}

// ------------------------------------------------------------------
// Kernel 1: particle encoder, one block per batch element, 256 threads.
// ------------------------------------------------------------------
__global__ __launch_bounds__(256, 4) void k_encoder(
    const float* __restrict__ x,
    const float* __restrict__ w1, const float* __restrict__ b1,
    const float* __restrict__ w2, const float* __restrict__ b2,
    float* __restrict__ xp)
{
    __shared__ __align__(16) float h1s[32 * 260];   // 33280 B
    const int tid  = threadIdx.x;
    const int b    = blockIdx.x;
    const int lane = tid & 63;
    const int wv   = tid >> 6;          // wave 0..3 -> 64-col slice
    const int cg   = lane & 15;         // col-group (4 cols)
    const int rg   = lane >> 4;         // row-group 0..3 (8 rows each)
    const int col0 = wv * 64 + cg * 4;

    const float* xb  = x + (size_t)b * (NPART * PSZ);
    const float* w1c = w1 + col0;
    const float* w2c = w2 + col0;
    const float4 b1v = *(const float4*)&b1[col0];
    const float4 b2v = *(const float4*)&b2[col0];

    float4 ms = make_float4(0.f, 0.f, 0.f, 0.f);

    enc_chunk<8>(xb,  0, w1c, w2c, h1s, rg, col0, b1v, b2v, ms);
    enc_chunk<8>(xb, 32, w1c, w2c, h1s, rg, col0, b1v, b2v, ms);
    enc_chunk<8>(xb, 64, w1c, w2c, h1s, rg, col0, b1v, b2v, ms);
    enc_chunk<1>(xb, 96, w1c, w2c, h1s, rg, col0, b1v, b2v, ms);  // rows 96..99 = 96+rg

    // reduce across the 4 row-groups (lane bits 4,5)
    ms.x += __shfl_xor(ms.x, 16, 64); ms.x += __shfl_xor(ms.x, 32, 64);
    ms.y += __shfl_xor(ms.y, 16, 64); ms.y += __shfl_xor(ms.y, 32, 64);
    ms.z += __shfl_xor(ms.z, 16, 64); ms.z += __shfl_xor(ms.z, 32, 64);
    ms.w += __shfl_xor(ms.w, 16, 64); ms.w += __shfl_xor(ms.w, 32, 64);
    if (rg == 0) {
        float4 o = make_float4(ms.x / 100.f, ms.y / 100.f, ms.z / 100.f, ms.w / 100.f);
        *(float4*)&xp[(size_t)b * 256 + col0] = o;
    }
}

// ------------------------------------------------------------------
// Kernel 2: fc3..fc6 fused MLP, 8 rows per block (512 blocks) - unchanged
// ------------------------------------------------------------------
__global__ __launch_bounds__(256) void k_mlp(
    const float* __restrict__ cin, const float* __restrict__ xp,
    const float* __restrict__ w3, const float* __restrict__ b3,
    const float* __restrict__ w4, const float* __restrict__ b4,
    const float* __restrict__ w5, const float* __restrict__ b5,
    const float* __restrict__ w6, const float* __restrict__ b6,
    float* __restrict__ z)
{
    __shared__ float in0[8][320];
    __shared__ float h3[8][512];
    __shared__ float h4[8][256];
    __shared__ float h5[8][128];
    const int tid  = threadIdx.x;
    const int row0 = blockIdx.x * 8;

    for (int i = tid; i < 8 * 16; i += 256) {
        int r = i >> 4, q = i & 15;
        *(float4*)&in0[r][q * 4] = *(const float4*)&cin[(size_t)(row0 + r) * 64 + q * 4];
    }
    for (int i = tid; i < 8 * 64; i += 256) {
        int r = i >> 6, q = i & 63;
        *(float4*)&in0[r][64 + q * 4] = *(const float4*)&xp[(size_t)(row0 + r) * 256 + q * 4];
    }
    __syncthreads();

    {   // fc3: 320 -> 512, cols {tid, tid+256}
        float a0[8], a1[8];
        #pragma unroll
        for (int r = 0; r < 8; ++r) { a0[r] = 0.f; a1[r] = 0.f; }
        const int c0 = tid, c1 = tid + 256;
        for (int kq = 0; kq < 80; ++kq) {
            const int k0 = kq * 4;
            float wa0 = w3[(k0+0)*512 + c0], wa1 = w3[(k0+1)*512 + c0];
            float wa2 = w3[(k0+2)*512 + c0], wa3 = w3[(k0+3)*512 + c0];
            float wb0 = w3[(k0+0)*512 + c1], wb1 = w3[(k0+1)*512 + c1];
            float wb2 = w3[(k0+2)*512 + c1], wb3 = w3[(k0+3)*512 + c1];
            #pragma unroll
            for (int r = 0; r < 8; ++r) {
                const float4 a = *(const float4*)&in0[r][k0];
                a0[r] = fmaf(a.x, wa0, fmaf(a.y, wa1, fmaf(a.z, wa2, fmaf(a.w, wa3, a0[r]))));
                a1[r] = fmaf(a.x, wb0, fmaf(a.y, wb1, fmaf(a.z, wb2, fmaf(a.w, wb3, a1[r]))));
            }
        }
        const float bb0 = b3[c0], bb1 = b3[c1];
        #pragma unroll
        for (int r = 0; r < 8; ++r) {
            h3[r][c0] = fmaxf(a0[r] + bb0, 0.f);
            h3[r][c1] = fmaxf(a1[r] + bb1, 0.f);
        }
    }
    __syncthreads();

    {   // fc4: 512 -> 256
        float ac[8];
        #pragma unroll
        for (int r = 0; r < 8; ++r) ac[r] = 0.f;
        for (int kq = 0; kq < 128; ++kq) {
            const int k0 = kq * 4;
            float w0 = w4[(k0+0)*256 + tid], w1v = w4[(k0+1)*256 + tid];
            float w2v = w4[(k0+2)*256 + tid], w3v = w4[(k0+3)*256 + tid];
            #pragma unroll
            for (int r = 0; r < 8; ++r) {
                const float4 a = *(const float4*)&h3[r][k0];
                ac[r] = fmaf(a.x, w0, fmaf(a.y, w1v, fmaf(a.z, w2v, fmaf(a.w, w3v, ac[r]))));
            }
        }
        const float bb = b4[tid];
        #pragma unroll
        for (int r = 0; r < 8; ++r) h4[r][tid] = fmaxf(ac[r] + bb, 0.f);
    }
    __syncthreads();

    {   // fc5: 256 -> 128
        const int c5 = tid & 127, half = tid >> 7;
        float ac[4];
        #pragma unroll
        for (int r = 0; r < 4; ++r) ac[r] = 0.f;
        for (int kq = 0; kq < 64; ++kq) {
            const int k0 = kq * 4;
            float w0 = w5[(k0+0)*128 + c5], w1v = w5[(k0+1)*128 + c5];
            float w2v = w5[(k0+2)*128 + c5], w3v = w5[(k0+3)*128 + c5];
            #pragma unroll
            for (int r = 0; r < 4; ++r) {
                const float4 a = *(const float4*)&h4[half * 4 + r][k0];
                ac[r] = fmaf(a.x, w0, fmaf(a.y, w1v, fmaf(a.z, w2v, fmaf(a.w, w3v, ac[r]))));
            }
        }
        const float bb = b5[c5];
        #pragma unroll
        for (int r = 0; r < 4; ++r) h5[half * 4 + r][c5] = fmaxf(ac[r] + bb, 0.f);
    }
    __syncthreads();

    {   // fc6: 128 -> 32
        const int c6 = tid & 31, r = tid >> 5;
        float ac = 0.f;
        for (int kq = 0; kq < 32; ++kq) {
            const int k0 = kq * 4;
            float w0 = w6[(k0+0)*32 + c6], w1v = w6[(k0+1)*32 + c6];
            float w2v = w6[(k0+2)*32 + c6], w3v = w6[(k0+3)*32 + c6];
            const float4 a = *(const float4*)&h5[r][k0];
            ac = fmaf(a.x, w0, fmaf(a.y, w1v, fmaf(a.z, w2v, fmaf(a.w, w3v, ac))));
        }
        z[(size_t)(row0 + r) * 32 + c6] = fmaxf(ac + b6[c6], 0.f);
    }
}

// ------------------------------------------------------------------
// Prep kernel: transpose LSTM weights to gate-major k-contiguous layout,
// pre-sum biases, transpose w10. Runs every launch (graph-safe).
// wT layout: [l][q][k4][c][j] -> idx l*4096 + q*1024 + k4*128 + c*4 + j
//            = w[l][k4*4+j][q*32+c]
// ------------------------------------------------------------------
__global__ __launch_bounds__(256) void k_prep(
    const float* __restrict__ wih, const float* __restrict__ whh,
    const float* __restrict__ bih, const float* __restrict__ bhh,
    const float* __restrict__ w10,
    float* __restrict__ wihT, float* __restrict__ whhT,
    float* __restrict__ bsum, float* __restrict__ w10T)
{
    const int i = blockIdx.x * 256 + threadIdx.x;
    if (i < 6 * 4096) {
        const int l = i >> 12, r = i & 4095;
        const int q = r >> 10, k4 = (r >> 7) & 7, c = (r >> 2) & 31, j = r & 3;
        const int src = l * 4096 + (k4 * 4 + j) * 128 + q * 32 + c;
        wihT[i] = wih[src];
        whhT[i] = whh[src];
    }
    if (i < 361 * 32) {
        const int v = i >> 5, k = i & 31;
        w10T[i] = w10[k * 361 + v];
    }
    if (i < 768) bsum[i] = bih[i] + bhh[i];
}

// ------------------------------------------------------------------
// Kernel 3: LSTM, barrier-free per-wave design. 2048 blocks x 64 threads,
// each wave owns 2 batch rows for all 24 steps x 6 layers + fc10 + top-8.
// Thread (c = lane&31, rw = lane>>5) computes ALL 4 gates of cell (rw, c)
// -> cell update needs no cross-thread data; cell state in registers.
// h round-trips through wave-private LDS (in-order wave => no barrier).
// ------------------------------------------------------------------
__global__ __launch_bounds__(64, 4) void k_lstm(
    const float* __restrict__ z,
    const float* __restrict__ hid0, const float* __restrict__ cel0,
    const float* __restrict__ wihT, const float* __restrict__ whhT,
    const float* __restrict__ bsum, const float* __restrict__ w10T,
    const float* __restrict__ b10, int* __restrict__ out)
{
    __shared__ __align__(16) float cur[2][32];      // h_{l-1} / h5 carry
    __shared__ __align__(16) float hp[6][2][32];    // per-layer h state
    const int lane = threadIdx.x;
    const int c    = lane & 31;
    const int rw   = lane >> 5;
    const int row0 = blockIdx.x * 2;
    const int row  = row0 + rw;

    cur[rw][c] = z[(size_t)row * 32 + c];
    float creg[6];
    #pragma unroll
    for (int l = 0; l < 6; ++l) {
        hp[l][rw][c] = hid0[(size_t)l * BATCH * 32 + (size_t)row * 32 + c];
        creg[l]      = cel0[(size_t)l * BATCH * 32 + (size_t)row * 32 + c];
    }

    for (int t = 0; t < 24; ++t) {
        #pragma unroll
        for (int l = 0; l < 6; ++l) {
            float4 xi[8], hh[8];
            #pragma unroll
            for (int k4 = 0; k4 < 8; ++k4) {
                xi[k4] = *(const float4*)&cur[rw][k4 * 4];
                hh[k4] = *(const float4*)&hp[l][rw][k4 * 4];
            }
            const float* WI = wihT + l * 4096 + c * 4;
            const float* WH = whhT + l * 4096 + c * 4;
            float g4[4];
            #pragma unroll
            for (int q = 0; q < 4; ++q) {
                float acc = bsum[l * 128 + q * 32 + c];
                #pragma unroll
                for (int k4 = 0; k4 < 8; ++k4) {
                    const float4 wi = *(const float4*)(WI + q * 1024 + k4 * 128);
                    const float4 wh = *(const float4*)(WH + q * 1024 + k4 * 128);
                    acc = fmaf(xi[k4].x, wi.x, acc); acc = fmaf(xi[k4].y, wi.y, acc);
                    acc = fmaf(xi[k4].z, wi.z, acc); acc = fmaf(xi[k4].w, wi.w, acc);
                    acc = fmaf(hh[k4].x, wh.x, acc); acc = fmaf(hh[k4].y, wh.y, acc);
                    acc = fmaf(hh[k4].z, wh.z, acc); acc = fmaf(hh[k4].w, wh.w, acc);
                }
                g4[q] = acc;
            }
            const float i_ = 1.f / (1.f + expf(-g4[0]));
            const float f_ = 1.f / (1.f + expf(-g4[1]));
            const float g_ = tanhf(g4[2]);
            const float o_ = 1.f / (1.f + expf(-g4[3]));
            const float cn = f_ * creg[l] + i_ * g_;
            creg[l] = cn;
            const float hn = o_ * tanhf(cn);
            hp[l][rw][c] = hn;
            cur[rw][c]   = hn;
        }

        // ---- fc10 -> per-lane logits held in registers (no LDS round-trip)
        float val[2][6];
        #pragma unroll
        for (int s = 0; s < 6; ++s) {
            const int v = lane + 64 * s;
            if (v < 361) {
                const float* wv = w10T + v * 32;
                float a0 = b10[v], a1 = a0;
                #pragma unroll
                for (int k4 = 0; k4 < 8; ++k4) {
                    const float4 w  = *(const float4*)(wv + k4 * 4);
                    const float4 h0 = *(const float4*)&cur[0][k4 * 4];
                    const float4 h1 = *(const float4*)&cur[1][k4 * 4];
                    a0 = fmaf(h0.x, w.x, a0); a0 = fmaf(h0.y, w.y, a0);
                    a0 = fmaf(h0.z, w.z, a0); a0 = fmaf(h0.w, w.w, a0);
                    a1 = fmaf(h1.x, w.x, a1); a1 = fmaf(h1.y, w.y, a1);
                    a1 = fmaf(h1.z, w.z, a1); a1 = fmaf(h1.w, w.w, a1);
                }
                val[0][s] = a0; val[1][s] = a1;
            } else {
                val[0][s] = -3.4e38f; val[1][s] = -3.4e38f;
            }
        }

        // ---- top-8 per row (jax.lax.top_k: desc values, lower index wins ties)
        #pragma unroll
        for (int r = 0; r < 2; ++r) {
            unsigned msk = 0x3Fu;
            for (int sel = 0; sel < 8; ++sel) {
                float bv = -3.4e38f; int bi = 0x7FFFFFFF;
                #pragma unroll
                for (int s = 0; s < 6; ++s) {
                    if (msk & (1u << s)) {
                        const float v2 = val[r][s]; const int i2 = lane + 64 * s;
                        if (v2 > bv || (v2 == bv && i2 < bi)) { bv = v2; bi = i2; }
                    }
                }
                #pragma unroll
                for (int off = 32; off >= 1; off >>= 1) {
                    const float ov = __shfl_xor(bv, off, 64);
                    const int   oi = __shfl_xor(bi, off, 64);
                    if (ov > bv || (ov == bv && oi < bi)) { bv = ov; bi = oi; }
                }
                if ((bi & 63) == lane) msk &= ~(1u << (bi >> 6));
                if (lane == 0) out[(size_t)(row0 + r) * 192 + t * 8 + sel] = bi;
            }
        }
    }
}

// ------------------------------------------------------------------
extern "C" void kernel_launch(void* const* d_in, const int* in_sizes, int n_in,
                              void* d_out, int out_size, void* d_ws, size_t ws_size,
                              hipStream_t stream) {
    const float* cin  = (const float*)d_in[0];
    const float* x    = (const float*)d_in[1];
    const float* hid0 = (const float*)d_in[2];
    const float* cel0 = (const float*)d_in[3];
    const float* w1 = (const float*)d_in[4];  const float* b1 = (const float*)d_in[5];
    const float* w2 = (const float*)d_in[6];  const float* b2 = (const float*)d_in[7];
    const float* w3 = (const float*)d_in[8];  const float* b3 = (const float*)d_in[9];
    const float* w4 = (const float*)d_in[10]; const float* b4 = (const float*)d_in[11];
    const float* w5 = (const float*)d_in[12]; const float* b5 = (const float*)d_in[13];
    const float* w6 = (const float*)d_in[14]; const float* b6 = (const float*)d_in[15];
    const float* wih = (const float*)d_in[16]; const float* whh = (const float*)d_in[17];
    const float* bih = (const float*)d_in[18]; const float* bhh = (const float*)d_in[19];
    const float* w10 = (const float*)d_in[20]; const float* b10 = (const float*)d_in[21];

    float* xp   = (float*)d_ws;                       // 4096 x 256
    float* zz   = xp + (size_t)BATCH * 256;           // 4096 x 32
    float* wihT = zz + (size_t)BATCH * 32;            // 24576
    float* whhT = wihT + 6 * 4096;                    // 24576
    float* bsum = whhT + 6 * 4096;                    // 768
    float* w10T = bsum + 768;                         // 11552
    int*   out  = (int*)d_out;

    k_prep<<<96, 256, 0, stream>>>(wih, whh, bih, bhh, w10, wihT, whhT, bsum, w10T);
    k_encoder<<<BATCH, 256, 0, stream>>>(x, w1, b1, w2, b2, xp);
    k_mlp<<<BATCH / 8, 256, 0, stream>>>(cin, xp, w3, b3, w4, b4, w5, b5, w6, b6, zz);
    k_lstm<<<BATCH / 2, 64, 0, stream>>>(zz, hid0, cel0, wihT, whhT, bsum, w10T, b10, out);
}

// Round 6
// 6486.520 us; speedup vs baseline: 1.1204x; 1.1204x over previous
//
#include <hip/hip_runtime.h>
#include <math.h>

#define BATCH 4096
#define NPART 100
#define PSZ   64
#define VOCAB 361

__device__ __forceinline__ void fma4(float4& d, const float s, const float4 v) {
    d.x = fmaf(s, v.x, d.x); d.y = fmaf(s, v.y, d.y);
    d.z = fmaf(s, v.z, d.z); d.w = fmaf(s, v.w, d.w);
}
__device__ __forceinline__ float4 addrelu4(const float4 a, const float4 b) {
    return make_float4(fmaxf(a.x + b.x, 0.f), fmaxf(a.y + b.y, 0.f),
                       fmaxf(a.z + b.z, 0.f), fmaxf(a.w + b.w, 0.f));
}

// ------------------------------------------------------------------
// Encoder chunk worker (v5 tile): lane = (rg 0..3, cg 0..15),
// 8 rows x 4 cols. 4 W-loads + 8 A-loads per 128 FMAs.
// ------------------------------------------------------------------
template<int NJ>
__device__ __forceinline__ void enc_chunk(
    const float* __restrict__ xb, const int rbase,
    const float* __restrict__ w1c, const float* __restrict__ w2c,
    float* __restrict__ h1s, const int rg, const int col0,
    const float4 b1v, const float4 b2v, float4& msum)
{
    // ---- fc1: h1 = relu(x @ W1 + b1), K=64
    float4 acc1[NJ];
    #pragma unroll
    for (int j = 0; j < NJ; ++j) acc1[j] = make_float4(0.f, 0.f, 0.f, 0.f);
    #pragma unroll 2
    for (int k0 = 0; k0 < 64; k0 += 4) {
        float4 w[4];
        #pragma unroll
        for (int kk = 0; kk < 4; ++kk)
            w[kk] = *(const float4*)(w1c + (k0 + kk) * 256);
        #pragma unroll
        for (int j = 0; j < NJ; ++j) {
            const float4 a = *(const float4*)(xb + (size_t)(rbase + rg + 4 * j) * 64 + k0);
            fma4(acc1[j], a.x, w[0]); fma4(acc1[j], a.y, w[1]);
            fma4(acc1[j], a.z, w[2]); fma4(acc1[j], a.w, w[3]);
        }
    }
    #pragma unroll
    for (int j = 0; j < NJ; ++j)
        *(float4*)&h1s[(rg + 4 * j) * 260 + col0] = addrelu4(acc1[j], b1v);
    __syncthreads();

    // ---- fc2: K=256, A from LDS (broadcast, conflict-free), B from global
    float4 acc2[NJ];
    #pragma unroll
    for (int j = 0; j < NJ; ++j) acc2[j] = make_float4(0.f, 0.f, 0.f, 0.f);
    #pragma unroll 2
    for (int k0 = 0; k0 < 256; k0 += 4) {
        float4 w[4];
        #pragma unroll
        for (int kk = 0; kk < 4; ++kk)
            w[kk] = *(const float4*)(w2c + (k0 + kk) * 256);
        #pragma unroll
        for (int j = 0; j < NJ; ++j) {
            const float4 a = *(const float4*)&h1s[(rg + 4 * j) * 260 + k0];
            fma4(acc2[j], a.x, w[0]); fma4(acc2[j], a.y, w[1]);
            fma4(acc2[j], a.z, w[2]); fma4(acc2[j], a.w, w[3]);
        }
    }
    #pragma unroll
    for (int j = 0; j < NJ; ++j) {
        const float4 r = addrelu4(acc2[j], b2v);
        msum.x += r.x; msum.y += r.y; msum.z += r.z; msum.w += r.w;
    }
    __syncthreads();
}

// ------------------------------------------------------------------
// Kernel 1: particle encoder, one block per batch element.
// ------------------------------------------------------------------
__global__ __launch_bounds__(256, 4) void k_encoder(
    const float* __restrict__ x,
    const float* __restrict__ w1, const float* __restrict__ b1,
    const float* __restrict__ w2, const float* __restrict__ b2,
    float* __restrict__ xp)
{
    __shared__ __align__(16) float h1s[32 * 260];   // 33280 B
    const int tid  = threadIdx.x;
    const int b    = blockIdx.x;
    const int lane = tid & 63;
    const int wv   = tid >> 6;
    const int cg   = lane & 15;
    const int rg   = lane >> 4;
    const int col0 = wv * 64 + cg * 4;

    const float* xb  = x + (size_t)b * (NPART * PSZ);
    const float* w1c = w1 + col0;
    const float* w2c = w2 + col0;
    const float4 b1v = *(const float4*)&b1[col0];
    const float4 b2v = *(const float4*)&b2[col0];

    float4 ms = make_float4(0.f, 0.f, 0.f, 0.f);

    enc_chunk<8>(xb,  0, w1c, w2c, h1s, rg, col0, b1v, b2v, ms);
    enc_chunk<8>(xb, 32, w1c, w2c, h1s, rg, col0, b1v, b2v, ms);
    enc_chunk<8>(xb, 64, w1c, w2c, h1s, rg, col0, b1v, b2v, ms);
    enc_chunk<1>(xb, 96, w1c, w2c, h1s, rg, col0, b1v, b2v, ms);

    ms.x += __shfl_xor(ms.x, 16, 64); ms.x += __shfl_xor(ms.x, 32, 64);
    ms.y += __shfl_xor(ms.y, 16, 64); ms.y += __shfl_xor(ms.y, 32, 64);
    ms.z += __shfl_xor(ms.z, 16, 64); ms.z += __shfl_xor(ms.z, 32, 64);
    ms.w += __shfl_xor(ms.w, 16, 64); ms.w += __shfl_xor(ms.w, 32, 64);
    if (rg == 0) {
        float4 o = make_float4(ms.x / 100.f, ms.y / 100.f, ms.z / 100.f, ms.w / 100.f);
        *(float4*)&xp[(size_t)b * 256 + col0] = o;
    }
}

// ------------------------------------------------------------------
// Kernel 2: fc3..fc6 fused MLP, 8 rows per block (512 blocks)
// ------------------------------------------------------------------
__global__ __launch_bounds__(256) void k_mlp(
    const float* __restrict__ cin, const float* __restrict__ xp,
    const float* __restrict__ w3, const float* __restrict__ b3,
    const float* __restrict__ w4, const float* __restrict__ b4,
    const float* __restrict__ w5, const float* __restrict__ b5,
    const float* __restrict__ w6, const float* __restrict__ b6,
    float* __restrict__ z)
{
    __shared__ float in0[8][320];
    __shared__ float h3[8][512];
    __shared__ float h4[8][256];
    __shared__ float h5[8][128];
    const int tid  = threadIdx.x;
    const int row0 = blockIdx.x * 8;

    for (int i = tid; i < 8 * 16; i += 256) {
        int r = i >> 4, q = i & 15;
        *(float4*)&in0[r][q * 4] = *(const float4*)&cin[(size_t)(row0 + r) * 64 + q * 4];
    }
    for (int i = tid; i < 8 * 64; i += 256) {
        int r = i >> 6, q = i & 63;
        *(float4*)&in0[r][64 + q * 4] = *(const float4*)&xp[(size_t)(row0 + r) * 256 + q * 4];
    }
    __syncthreads();

    {   // fc3: 320 -> 512, cols {tid, tid+256}
        float a0[8], a1[8];
        #pragma unroll
        for (int r = 0; r < 8; ++r) { a0[r] = 0.f; a1[r] = 0.f; }
        const int c0 = tid, c1 = tid + 256;
        for (int kq = 0; kq < 80; ++kq) {
            const int k0 = kq * 4;
            float wa0 = w3[(k0+0)*512 + c0], wa1 = w3[(k0+1)*512 + c0];
            float wa2 = w3[(k0+2)*512 + c0], wa3 = w3[(k0+3)*512 + c0];
            float wb0 = w3[(k0+0)*512 + c1], wb1 = w3[(k0+1)*512 + c1];
            float wb2 = w3[(k0+2)*512 + c1], wb3 = w3[(k0+3)*512 + c1];
            #pragma unroll
            for (int r = 0; r < 8; ++r) {
                const float4 a = *(const float4*)&in0[r][k0];
                a0[r] = fmaf(a.x, wa0, fmaf(a.y, wa1, fmaf(a.z, wa2, fmaf(a.w, wa3, a0[r]))));
                a1[r] = fmaf(a.x, wb0, fmaf(a.y, wb1, fmaf(a.z, wb2, fmaf(a.w, wb3, a1[r]))));
            }
        }
        const float bb0 = b3[c0], bb1 = b3[c1];
        #pragma unroll
        for (int r = 0; r < 8; ++r) {
            h3[r][c0] = fmaxf(a0[r] + bb0, 0.f);
            h3[r][c1] = fmaxf(a1[r] + bb1, 0.f);
        }
    }
    __syncthreads();

    {   // fc4: 512 -> 256
        float ac[8];
        #pragma unroll
        for (int r = 0; r < 8; ++r) ac[r] = 0.f;
        for (int kq = 0; kq < 128; ++kq) {
            const int k0 = kq * 4;
            float w0 = w4[(k0+0)*256 + tid], w1v = w4[(k0+1)*256 + tid];
            float w2v = w4[(k0+2)*256 + tid], w3v = w4[(k0+3)*256 + tid];
            #pragma unroll
            for (int r = 0; r < 8; ++r) {
                const float4 a = *(const float4*)&h3[r][k0];
                ac[r] = fmaf(a.x, w0, fmaf(a.y, w1v, fmaf(a.z, w2v, fmaf(a.w, w3v, ac[r]))));
            }
        }
        const float bb = b4[tid];
        #pragma unroll
        for (int r = 0; r < 8; ++r) h4[r][tid] = fmaxf(ac[r] + bb, 0.f);
    }
    __syncthreads();

    {   // fc5: 256 -> 128
        const int c5 = tid & 127, half = tid >> 7;
        float ac[4];
        #pragma unroll
        for (int r = 0; r < 4; ++r) ac[r] = 0.f;
        for (int kq = 0; kq < 64; ++kq) {
            const int k0 = kq * 4;
            float w0 = w5[(k0+0)*128 + c5], w1v = w5[(k0+1)*128 + c5];
            float w2v = w5[(k0+2)*128 + c5], w3v = w5[(k0+3)*128 + c5];
            #pragma unroll
            for (int r = 0; r < 4; ++r) {
                const float4 a = *(const float4*)&h4[half * 4 + r][k0];
                ac[r] = fmaf(a.x, w0, fmaf(a.y, w1v, fmaf(a.z, w2v, fmaf(a.w, w3v, ac[r]))));
            }
        }
        const float bb = b5[c5];
        #pragma unroll
        for (int r = 0; r < 4; ++r) h5[half * 4 + r][c5] = fmaxf(ac[r] + bb, 0.f);
    }
    __syncthreads();

    {   // fc6: 128 -> 32
        const int c6 = tid & 31, r = tid >> 5;
        float ac = 0.f;
        for (int kq = 0; kq < 32; ++kq) {
            const int k0 = kq * 4;
            float w0 = w6[(k0+0)*32 + c6], w1v = w6[(k0+1)*32 + c6];
            float w2v = w6[(k0+2)*32 + c6], w3v = w6[(k0+3)*32 + c6];
            const float4 a = *(const float4*)&h5[r][k0];
            ac = fmaf(a.x, w0, fmaf(a.y, w1v, fmaf(a.z, w2v, fmaf(a.w, w3v, ac))));
        }
        z[(size_t)(row0 + r) * 32 + c6] = fmaxf(ac + b6[c6], 0.f);
    }
}

// ------------------------------------------------------------------
// Kernel 3: LSTM v3 — wave-local, weights from d_in (cacheable!).
// 512 blocks x 256 threads = 4 waves x 2 rows. Per layer:
//  phase 1: lane j computes gate-cols 4j..4j+3 of its row via float4
//           loads on the ORIGINAL [k][128] weight layout (L1/L2-hot);
//           gates go to wave-private LDS gbuf (no barrier needed).
//  phase 2: lane c reads its cell's 4 gates, updates c/h (regs/LDS).
// fc10 weights staged once in LDS as [v][33-padded k] (47.6KB);
// one __syncthreads per step keeps waves layer-aligned for L1 reuse.
// ------------------------------------------------------------------
__global__ __launch_bounds__(256, 2) void k_lstm(
    const float* __restrict__ z,
    const float* __restrict__ hid0, const float* __restrict__ cel0,
    const float* __restrict__ wih, const float* __restrict__ whh,
    const float* __restrict__ bih, const float* __restrict__ bhh,
    const float* __restrict__ w10, const float* __restrict__ b10,
    int* __restrict__ out)
{
    __shared__ __align__(16) float w10t[VOCAB * 33];   // [v][k] padded
    __shared__ float b10s[VOCAB];
    __shared__ __align__(16) float bsums[768];
    __shared__ __align__(16) float curs[4][2][32];
    __shared__ __align__(16) float hps[4][6][2][32];
    __shared__ __align__(16) float gbuf[4][2][128];

    const int tid  = threadIdx.x;
    const int w    = tid >> 6;
    const int lane = tid & 63;
    const int rw   = lane >> 5;
    const int c    = lane & 31;
    const int row0 = blockIdx.x * 8 + w * 2;
    const int row  = row0 + rw;

    for (int i = tid; i < VOCAB * 32; i += 256) {
        const int v = i >> 5, k = i & 31;
        w10t[v * 33 + k] = w10[k * VOCAB + v];
    }
    for (int i = tid; i < VOCAB; i += 256) b10s[i] = b10[i];
    for (int i = tid; i < 768; i += 256)   bsums[i] = bih[i] + bhh[i];

    curs[w][rw][c] = z[(size_t)row * 32 + c];
    float creg[6];
    #pragma unroll
    for (int l = 0; l < 6; ++l) {
        hps[w][l][rw][c] = hid0[(size_t)l * BATCH * 32 + (size_t)row * 32 + c];
        creg[l]          = cel0[(size_t)l * BATCH * 32 + (size_t)row * 32 + c];
    }
    __syncthreads();

    for (int t = 0; t < 24; ++t) {
        #pragma unroll
        for (int l = 0; l < 6; ++l) {
            // ---- phase 1: gates for cols 4c..4c+3 of row rw
            float4 xi[8], hh8[8];
            #pragma unroll
            for (int k4 = 0; k4 < 8; ++k4) {
                xi[k4]  = *(const float4*)&curs[w][rw][k4 * 4];
                hh8[k4] = *(const float4*)&hps[w][l][rw][k4 * 4];
            }
            const float* WI = wih + l * 4096 + c * 4;
            const float* WH = whh + l * 4096 + c * 4;
            float4 acc = *(const float4*)&bsums[l * 128 + c * 4];
            #pragma unroll
            for (int k4 = 0; k4 < 8; ++k4) {
                const int kb = k4 * 4;
                fma4(acc, xi[k4].x,  *(const float4*)(WI + (kb+0) * 128));
                fma4(acc, hh8[k4].x, *(const float4*)(WH + (kb+0) * 128));
                fma4(acc, xi[k4].y,  *(const float4*)(WI + (kb+1) * 128));
                fma4(acc, hh8[k4].y, *(const float4*)(WH + (kb+1) * 128));
                fma4(acc, xi[k4].z,  *(const float4*)(WI + (kb+2) * 128));
                fma4(acc, hh8[k4].z, *(const float4*)(WH + (kb+2) * 128));
                fma4(acc, xi[k4].w,  *(const float4*)(WI + (kb+3) * 128));
                fma4(acc, hh8[k4].w, *(const float4*)(WH + (kb+3) * 128));
            }
            *(float4*)&gbuf[w][rw][c * 4] = acc;

            // ---- phase 2: cell update (wave-internal LDS, no barrier)
            const float gi = gbuf[w][rw][c];
            const float gf = gbuf[w][rw][32 + c];
            const float gg = gbuf[w][rw][64 + c];
            const float go = gbuf[w][rw][96 + c];
            const float i_ = 1.f / (1.f + expf(-gi));
            const float f_ = 1.f / (1.f + expf(-gf));
            const float g_ = tanhf(gg);
            const float o_ = 1.f / (1.f + expf(-go));
            const float cn = f_ * creg[l] + i_ * g_;
            creg[l] = cn;
            const float hn = o_ * tanhf(cn);
            hps[w][l][rw][c] = hn;
            curs[w][rw][c]   = hn;
        }

        // ---- fc10: logits for both rows, from LDS-cached w10t
        float4 h0[8], h1[8];
        #pragma unroll
        for (int k4 = 0; k4 < 8; ++k4) {
            h0[k4] = *(const float4*)&curs[w][0][k4 * 4];
            h1[k4] = *(const float4*)&curs[w][1][k4 * 4];
        }
        float val[2][6];
        #pragma unroll
        for (int s = 0; s < 6; ++s) {
            const int v = lane + 64 * s;
            if (v < VOCAB) {
                const float* wv = &w10t[v * 33];
                float a0 = b10s[v], a1 = a0;
                #pragma unroll
                for (int k4 = 0; k4 < 8; ++k4) {
                    const float4 wk = *(const float4*)(wv + k4 * 4);
                    a0 = fmaf(h0[k4].x, wk.x, a0); a0 = fmaf(h0[k4].y, wk.y, a0);
                    a0 = fmaf(h0[k4].z, wk.z, a0); a0 = fmaf(h0[k4].w, wk.w, a0);
                    a1 = fmaf(h1[k4].x, wk.x, a1); a1 = fmaf(h1[k4].y, wk.y, a1);
                    a1 = fmaf(h1[k4].z, wk.z, a1); a1 = fmaf(h1[k4].w, wk.w, a1);
                }
                val[0][s] = a0; val[1][s] = a1;
            } else {
                val[0][s] = -3.4e38f; val[1][s] = -3.4e38f;
            }
        }

        // ---- top-8 per row (desc values, lower index wins ties)
        #pragma unroll
        for (int r = 0; r < 2; ++r) {
            unsigned msk = 0x3Fu;
            for (int sel = 0; sel < 8; ++sel) {
                float bv = -3.4e38f; int bi = 0x7FFFFFFF;
                #pragma unroll
                for (int s = 0; s < 6; ++s) {
                    if (msk & (1u << s)) {
                        const float v2 = val[r][s]; const int i2 = lane + 64 * s;
                        if (v2 > bv || (v2 == bv && i2 < bi)) { bv = v2; bi = i2; }
                    }
                }
                #pragma unroll
                for (int off = 32; off >= 1; off >>= 1) {
                    const float ov = __shfl_xor(bv, off, 64);
                    const int   oi = __shfl_xor(bi, off, 64);
                    if (ov > bv || (ov == bv && oi < bi)) { bv = ov; bi = oi; }
                }
                if ((bi & 63) == lane) msk &= ~(1u << (bi >> 6));
                if (lane == 0) out[(size_t)(row0 + r) * 192 + t * 8 + sel] = bi;
            }
        }
        __syncthreads();   // keep the block's waves layer-aligned (L1 reuse)
    }
}

// ------------------------------------------------------------------
extern "C" void kernel_launch(void* const* d_in, const int* in_sizes, int n_in,
                              void* d_out, int out_size, void* d_ws, size_t ws_size,
                              hipStream_t stream) {
    const float* cin  = (const float*)d_in[0];
    const float* x    = (const float*)d_in[1];
    const float* hid0 = (const float*)d_in[2];
    const float* cel0 = (const float*)d_in[3];
    const float* w1 = (const float*)d_in[4];  const float* b1 = (const float*)d_in[5];
    const float* w2 = (const float*)d_in[6];  const float* b2 = (const float*)d_in[7];
    const float* w3 = (const float*)d_in[8];  const float* b3 = (const float*)d_in[9];
    const float* w4 = (const float*)d_in[10]; const float* b4 = (const float*)d_in[11];
    const float* w5 = (const float*)d_in[12]; const float* b5 = (const float*)d_in[13];
    const float* w6 = (const float*)d_in[14]; const float* b6 = (const float*)d_in[15];
    const float* wih = (const float*)d_in[16]; const float* whh = (const float*)d_in[17];
    const float* bih = (const float*)d_in[18]; const float* bhh = (const float*)d_in[19];
    const float* w10 = (const float*)d_in[20]; const float* b10 = (const float*)d_in[21];

    float* xp = (float*)d_ws;                       // 4096 x 256
    float* zz = xp + (size_t)BATCH * 256;           // 4096 x 32
    int*   out = (int*)d_out;

    k_encoder<<<BATCH, 256, 0, stream>>>(x, w1, b1, w2, b2, xp);
    k_mlp<<<BATCH / 8, 256, 0, stream>>>(cin, xp, w3, b3, w4, b4, w5, b5, w6, b6, zz);
    k_lstm<<<BATCH / 8, 256, 0, stream>>>(zz, hid0, cel0, wih, whh, bih, bhh, w10, b10, out);
}

// Round 7
// 2366.852 us; speedup vs baseline: 3.0705x; 2.7406x over previous
//
#include <hip/hip_runtime.h>
#include <math.h>

#define BATCH 4096
#define NPART 100
#define PSZ   64
#define VOCAB 361

__device__ __forceinline__ void fma4(float4& d, const float s, const float4 v) {
    d.x = fmaf(s, v.x, d.x); d.y = fmaf(s, v.y, d.y);
    d.z = fmaf(s, v.z, d.z); d.w = fmaf(s, v.w, d.w);
}
__device__ __forceinline__ float4 addrelu4(const float4 a, const float4 b) {
    return make_float4(fmaxf(a.x + b.x, 0.f), fmaxf(a.y + b.y, 0.f),
                       fmaxf(a.z + b.z, 0.f), fmaxf(a.w + b.w, 0.f));
}

// ------------------------------------------------------------------
// Encoder chunk worker (v5 tile, unchanged)
// ------------------------------------------------------------------
template<int NJ>
__device__ __forceinline__ void enc_chunk(
    const float* __restrict__ xb, const int rbase,
    const float* __restrict__ w1c, const float* __restrict__ w2c,
    float* __restrict__ h1s, const int rg, const int col0,
    const float4 b1v, const float4 b2v, float4& msum)
{
    float4 acc1[NJ];
    #pragma unroll
    for (int j = 0; j < NJ; ++j) acc1[j] = make_float4(0.f, 0.f, 0.f, 0.f);
    #pragma unroll 2
    for (int k0 = 0; k0 < 64; k0 += 4) {
        float4 w[4];
        #pragma unroll
        for (int kk = 0; kk < 4; ++kk)
            w[kk] = *(const float4*)(w1c + (k0 + kk) * 256);
        #pragma unroll
        for (int j = 0; j < NJ; ++j) {
            const float4 a = *(const float4*)(xb + (size_t)(rbase + rg + 4 * j) * 64 + k0);
            fma4(acc1[j], a.x, w[0]); fma4(acc1[j], a.y, w[1]);
            fma4(acc1[j], a.z, w[2]); fma4(acc1[j], a.w, w[3]);
        }
    }
    #pragma unroll
    for (int j = 0; j < NJ; ++j)
        *(float4*)&h1s[(rg + 4 * j) * 260 + col0] = addrelu4(acc1[j], b1v);
    __syncthreads();

    float4 acc2[NJ];
    #pragma unroll
    for (int j = 0; j < NJ; ++j) acc2[j] = make_float4(0.f, 0.f, 0.f, 0.f);
    #pragma unroll 2
    for (int k0 = 0; k0 < 256; k0 += 4) {
        float4 w[4];
        #pragma unroll
        for (int kk = 0; kk < 4; ++kk)
            w[kk] = *(const float4*)(w2c + (k0 + kk) * 256);
        #pragma unroll
        for (int j = 0; j < NJ; ++j) {
            const float4 a = *(const float4*)&h1s[(rg + 4 * j) * 260 + k0];
            fma4(acc2[j], a.x, w[0]); fma4(acc2[j], a.y, w[1]);
            fma4(acc2[j], a.z, w[2]); fma4(acc2[j], a.w, w[3]);
        }
    }
    #pragma unroll
    for (int j = 0; j < NJ; ++j) {
        const float4 r = addrelu4(acc2[j], b2v);
        msum.x += r.x; msum.y += r.y; msum.z += r.z; msum.w += r.w;
    }
    __syncthreads();
}

// ------------------------------------------------------------------
// Kernel 1: particle encoder (unchanged from R5/R6)
// ------------------------------------------------------------------
__global__ __launch_bounds__(256, 4) void k_encoder(
    const float* __restrict__ x,
    const float* __restrict__ w1, const float* __restrict__ b1,
    const float* __restrict__ w2, const float* __restrict__ b2,
    float* __restrict__ xp)
{
    __shared__ __align__(16) float h1s[32 * 260];
    const int tid  = threadIdx.x;
    const int b    = blockIdx.x;
    const int lane = tid & 63;
    const int wv   = tid >> 6;
    const int cg   = lane & 15;
    const int rg   = lane >> 4;
    const int col0 = wv * 64 + cg * 4;

    const float* xb  = x + (size_t)b * (NPART * PSZ);
    const float* w1c = w1 + col0;
    const float* w2c = w2 + col0;
    const float4 b1v = *(const float4*)&b1[col0];
    const float4 b2v = *(const float4*)&b2[col0];

    float4 ms = make_float4(0.f, 0.f, 0.f, 0.f);

    enc_chunk<8>(xb,  0, w1c, w2c, h1s, rg, col0, b1v, b2v, ms);
    enc_chunk<8>(xb, 32, w1c, w2c, h1s, rg, col0, b1v, b2v, ms);
    enc_chunk<8>(xb, 64, w1c, w2c, h1s, rg, col0, b1v, b2v, ms);
    enc_chunk<1>(xb, 96, w1c, w2c, h1s, rg, col0, b1v, b2v, ms);

    ms.x += __shfl_xor(ms.x, 16, 64); ms.x += __shfl_xor(ms.x, 32, 64);
    ms.y += __shfl_xor(ms.y, 16, 64); ms.y += __shfl_xor(ms.y, 32, 64);
    ms.z += __shfl_xor(ms.z, 16, 64); ms.z += __shfl_xor(ms.z, 32, 64);
    ms.w += __shfl_xor(ms.w, 16, 64); ms.w += __shfl_xor(ms.w, 32, 64);
    if (rg == 0) {
        float4 o = make_float4(ms.x / 100.f, ms.y / 100.f, ms.z / 100.f, ms.w / 100.f);
        *(float4*)&xp[(size_t)b * 256 + col0] = o;
    }
}

// ------------------------------------------------------------------
// Kernel 2: fc3..fc6 fused MLP (unchanged)
// ------------------------------------------------------------------
__global__ __launch_bounds__(256) void k_mlp(
    const float* __restrict__ cin, const float* __restrict__ xp,
    const float* __restrict__ w3, const float* __restrict__ b3,
    const float* __restrict__ w4, const float* __restrict__ b4,
    const float* __restrict__ w5, const float* __restrict__ b5,
    const float* __restrict__ w6, const float* __restrict__ b6,
    float* __restrict__ z)
{
    __shared__ float in0[8][320];
    __shared__ float h3[8][512];
    __shared__ float h4[8][256];
    __shared__ float h5[8][128];
    const int tid  = threadIdx.x;
    const int row0 = blockIdx.x * 8;

    for (int i = tid; i < 8 * 16; i += 256) {
        int r = i >> 4, q = i & 15;
        *(float4*)&in0[r][q * 4] = *(const float4*)&cin[(size_t)(row0 + r) * 64 + q * 4];
    }
    for (int i = tid; i < 8 * 64; i += 256) {
        int r = i >> 6, q = i & 63;
        *(float4*)&in0[r][64 + q * 4] = *(const float4*)&xp[(size_t)(row0 + r) * 256 + q * 4];
    }
    __syncthreads();

    {   // fc3: 320 -> 512
        float a0[8], a1[8];
        #pragma unroll
        for (int r = 0; r < 8; ++r) { a0[r] = 0.f; a1[r] = 0.f; }
        const int c0 = tid, c1 = tid + 256;
        for (int kq = 0; kq < 80; ++kq) {
            const int k0 = kq * 4;
            float wa0 = w3[(k0+0)*512 + c0], wa1 = w3[(k0+1)*512 + c0];
            float wa2 = w3[(k0+2)*512 + c0], wa3 = w3[(k0+3)*512 + c0];
            float wb0 = w3[(k0+0)*512 + c1], wb1 = w3[(k0+1)*512 + c1];
            float wb2 = w3[(k0+2)*512 + c1], wb3 = w3[(k0+3)*512 + c1];
            #pragma unroll
            for (int r = 0; r < 8; ++r) {
                const float4 a = *(const float4*)&in0[r][k0];
                a0[r] = fmaf(a.x, wa0, fmaf(a.y, wa1, fmaf(a.z, wa2, fmaf(a.w, wa3, a0[r]))));
                a1[r] = fmaf(a.x, wb0, fmaf(a.y, wb1, fmaf(a.z, wb2, fmaf(a.w, wb3, a1[r]))));
            }
        }
        const float bb0 = b3[c0], bb1 = b3[c1];
        #pragma unroll
        for (int r = 0; r < 8; ++r) {
            h3[r][c0] = fmaxf(a0[r] + bb0, 0.f);
            h3[r][c1] = fmaxf(a1[r] + bb1, 0.f);
        }
    }
    __syncthreads();

    {   // fc4: 512 -> 256
        float ac[8];
        #pragma unroll
        for (int r = 0; r < 8; ++r) ac[r] = 0.f;
        for (int kq = 0; kq < 128; ++kq) {
            const int k0 = kq * 4;
            float w0 = w4[(k0+0)*256 + tid], w1v = w4[(k0+1)*256 + tid];
            float w2v = w4[(k0+2)*256 + tid], w3v = w4[(k0+3)*256 + tid];
            #pragma unroll
            for (int r = 0; r < 8; ++r) {
                const float4 a = *(const float4*)&h3[r][k0];
                ac[r] = fmaf(a.x, w0, fmaf(a.y, w1v, fmaf(a.z, w2v, fmaf(a.w, w3v, ac[r]))));
            }
        }
        const float bb = b4[tid];
        #pragma unroll
        for (int r = 0; r < 8; ++r) h4[r][tid] = fmaxf(ac[r] + bb, 0.f);
    }
    __syncthreads();

    {   // fc5: 256 -> 128
        const int c5 = tid & 127, half = tid >> 7;
        float ac[4];
        #pragma unroll
        for (int r = 0; r < 4; ++r) ac[r] = 0.f;
        for (int kq = 0; kq < 64; ++kq) {
            const int k0 = kq * 4;
            float w0 = w5[(k0+0)*128 + c5], w1v = w5[(k0+1)*128 + c5];
            float w2v = w5[(k0+2)*128 + c5], w3v = w5[(k0+3)*128 + c5];
            #pragma unroll
            for (int r = 0; r < 4; ++r) {
                const float4 a = *(const float4*)&h4[half * 4 + r][k0];
                ac[r] = fmaf(a.x, w0, fmaf(a.y, w1v, fmaf(a.z, w2v, fmaf(a.w, w3v, ac[r]))));
            }
        }
        const float bb = b5[c5];
        #pragma unroll
        for (int r = 0; r < 4; ++r) h5[half * 4 + r][c5] = fmaxf(ac[r] + bb, 0.f);
    }
    __syncthreads();

    {   // fc6: 128 -> 32
        const int c6 = tid & 31, r = tid >> 5;
        float ac = 0.f;
        for (int kq = 0; kq < 32; ++kq) {
            const int k0 = kq * 4;
            float w0 = w6[(k0+0)*32 + c6], w1v = w6[(k0+1)*32 + c6];
            float w2v = w6[(k0+2)*32 + c6], w3v = w6[(k0+3)*32 + c6];
            const float4 a = *(const float4*)&h5[r][k0];
            ac = fmaf(a.x, w0, fmaf(a.y, w1v, fmaf(a.z, w2v, fmaf(a.w, w3v, ac))));
        }
        z[(size_t)(row0 + r) * 32 + c6] = fmaxf(ac + b6[c6], 0.f);
    }
}

// ------------------------------------------------------------------
// Kernel 3: LSTM v4 — per-layer block-wide LDS weight staging.
// 256 blocks x 256 threads; block owns 16 rows, wave owns 4 rows.
// Per layer: stage wih_l||whh_l (32KB) into LDS coalesced; each wave
// computes gates for its 4 rows wave-locally (lane = (j cols, lh K-half),
// halves combined via shfl_xor 32), cell update wave-local with cell
// state in registers (creg[6][2]). 2 barriers/layer. h5 -> d_ws.
// LDS = 32K wbuf + 12K hp + 2K cur + 8K gbuf + 3K bsums = 57.1 KB.
// ------------------------------------------------------------------
__global__ __launch_bounds__(256) void k_lstm(
    const float* __restrict__ z,
    const float* __restrict__ hid0, const float* __restrict__ cel0,
    const float* __restrict__ wih, const float* __restrict__ whh,
    const float* __restrict__ bih, const float* __restrict__ bhh,
    float* __restrict__ h5s)
{
    __shared__ __align__(16) float wbuf[8192];       // [lh][k][128]
    __shared__ __align__(16) float hp[6 * 16 * 32];  // per-layer h state
    __shared__ __align__(16) float cur[16 * 32];     // layer input / h carry
    __shared__ __align__(16) float gbuf[4][4][128];  // wave-private gates
    __shared__ float bsums[768];

    const int tid  = threadIdx.x;
    const int w    = tid >> 6;
    const int lane = tid & 63;
    const int j    = lane & 31;     // gate col-group (4 cols)
    const int lh   = lane >> 5;     // K-half: 0 = x@wih(+bias), 1 = h@whh
    const int c    = lane & 31;     // cell col
    const int rloc = lane >> 5;     // cell row select
    const int row0 = blockIdx.x * 16;

    for (int i = tid; i < 16 * 32; i += 256) cur[i] = z[(size_t)row0 * 32 + i];
    for (int i = tid; i < 6 * 16 * 32; i += 256) {
        const int l = i >> 9, rr = (i >> 5) & 15, cc = i & 31;
        hp[i] = hid0[(size_t)l * BATCH * 32 + (size_t)(row0 + rr) * 32 + cc];
    }
    for (int i = tid; i < 768; i += 256) bsums[i] = bih[i] + bhh[i];

    const int gA = row0 + 4 * w + rloc;   // wave-local rows: rloc, rloc+2
    const int gB = gA + 2;
    float creg[6][2];
    #pragma unroll
    for (int l = 0; l < 6; ++l) {
        creg[l][0] = cel0[(size_t)l * BATCH * 32 + (size_t)gA * 32 + c];
        creg[l][1] = cel0[(size_t)l * BATCH * 32 + (size_t)gB * 32 + c];
    }
    __syncthreads();

    const float4* wi4 = (const float4*)wih;
    const float4* wh4 = (const float4*)whh;

    for (int t = 0; t < 24; ++t) {
        float h5A = 0.f, h5B = 0.f;
        #pragma unroll
        for (int l = 0; l < 6; ++l) {
            {   // ---- stage layer weights into LDS (coalesced, block-wide)
                float4* dst = (float4*)wbuf;
                for (int i = tid; i < 2048; i += 256)
                    dst[i] = (i < 1024) ? wi4[l * 1024 + i] : wh4[l * 1024 + (i - 1024)];
            }
            __syncthreads();

            // ---- gate phase: 4 rows x 4 cols, K-half lh
            float4 acc[4];
            if (lh == 0) {
                const float4 bv = *(const float4*)&bsums[l * 128 + 4 * j];
                #pragma unroll
                for (int r = 0; r < 4; ++r) acc[r] = bv;
            } else {
                #pragma unroll
                for (int r = 0; r < 4; ++r) acc[r] = make_float4(0.f, 0.f, 0.f, 0.f);
            }
            const float* wb    = wbuf + lh * 4096 + 4 * j;
            const float* xbase = (lh == 0) ? cur : (hp + l * 512);
            #pragma unroll
            for (int k0 = 0; k0 < 32; k0 += 4) {
                float4 wk[4];
                #pragma unroll
                for (int kk = 0; kk < 4; ++kk)
                    wk[kk] = *(const float4*)(wb + (k0 + kk) * 128);
                #pragma unroll
                for (int r = 0; r < 4; ++r) {
                    const float4 a = *(const float4*)&xbase[(4 * w + r) * 32 + k0];
                    fma4(acc[r], a.x, wk[0]); fma4(acc[r], a.y, wk[1]);
                    fma4(acc[r], a.z, wk[2]); fma4(acc[r], a.w, wk[3]);
                }
            }
            // combine x-half + h-half across the lh groups
            #pragma unroll
            for (int r = 0; r < 4; ++r) {
                acc[r].x += __shfl_xor(acc[r].x, 32, 64);
                acc[r].y += __shfl_xor(acc[r].y, 32, 64);
                acc[r].z += __shfl_xor(acc[r].z, 32, 64);
                acc[r].w += __shfl_xor(acc[r].w, 32, 64);
            }
            if (lh == 0) {
                #pragma unroll
                for (int r = 0; r < 4; ++r)
                    *(float4*)&gbuf[w][r][4 * j] = acc[r];
            }
            __builtin_amdgcn_wave_barrier();   // order LDS write->read in-wave

            // ---- cell phase (wave-local; cells (rloc,c) and (rloc+2,c))
            {
                const float giA = gbuf[w][rloc][c],      gfA = gbuf[w][rloc][32 + c];
                const float ggA = gbuf[w][rloc][64 + c], goA = gbuf[w][rloc][96 + c];
                const float giB = gbuf[w][rloc + 2][c],      gfB = gbuf[w][rloc + 2][32 + c];
                const float ggB = gbuf[w][rloc + 2][64 + c], goB = gbuf[w][rloc + 2][96 + c];
                const float iA = 1.f / (1.f + expf(-giA)), fA = 1.f / (1.f + expf(-gfA));
                const float gA_ = tanhf(ggA),              oA = 1.f / (1.f + expf(-goA));
                const float iB = 1.f / (1.f + expf(-giB)), fB = 1.f / (1.f + expf(-gfB));
                const float gB_ = tanhf(ggB),              oB = 1.f / (1.f + expf(-goB));
                const float cnA = fA * creg[l][0] + iA * gA_;
                const float cnB = fB * creg[l][1] + iB * gB_;
                creg[l][0] = cnA; creg[l][1] = cnB;
                const float hnA = oA * tanhf(cnA);
                const float hnB = oB * tanhf(cnB);
                const int lrA = 4 * w + rloc, lrB = lrA + 2;
                cur[lrA * 32 + c] = hnA;  hp[l * 512 + lrA * 32 + c] = hnA;
                cur[lrB * 32 + c] = hnB;  hp[l * 512 + lrB * 32 + c] = hnB;
                if (l == 5) { h5A = hnA; h5B = hnB; }
            }
            __syncthreads();   // all waves done reading wbuf before restage
        }
        // ---- emit h5 for this step (consumed by k_logits)
        h5s[(size_t)t * BATCH * 32 + (size_t)gA * 32 + c] = h5A;
        h5s[(size_t)t * BATCH * 32 + (size_t)gB * 32 + c] = h5B;
    }
}

// ------------------------------------------------------------------
// Kernel 4: fc10 + top-8 over all 24x4096 (t,b) items.
// 768 blocks x 256 threads; w10^T staged once per block in LDS
// ([v][33] padded, conflict-free); wave handles 2 items per iter.
// ------------------------------------------------------------------
__global__ __launch_bounds__(256) void k_logits(
    const float* __restrict__ h5s,
    const float* __restrict__ w10, const float* __restrict__ b10,
    int* __restrict__ out)
{
    __shared__ __align__(16) float w10t[VOCAB * 33];
    __shared__ float b10s[VOCAB];

    const int tid  = threadIdx.x;
    const int w    = tid >> 6;
    const int lane = tid & 63;

    for (int i = tid; i < VOCAB * 32; i += 256) {
        const int v = i >> 5, k = i & 31;
        w10t[v * 33 + k] = w10[k * VOCAB + v];
    }
    for (int i = tid; i < VOCAB; i += 256) b10s[i] = b10[i];
    __syncthreads();

    const int base = blockIdx.x * 128;
    for (int it = 0; it < 16; ++it) {
        const int it0 = base + it * 8 + w * 2;
        const int it1 = it0 + 1;

        float4 h0[8], h1[8];
        #pragma unroll
        for (int k4 = 0; k4 < 8; ++k4) {
            h0[k4] = *(const float4*)(h5s + (size_t)it0 * 32 + k4 * 4);
            h1[k4] = *(const float4*)(h5s + (size_t)it1 * 32 + k4 * 4);
        }

        float val[2][6];
        #pragma unroll
        for (int s = 0; s < 6; ++s) {
            const int v = lane + 64 * s;
            if (v < VOCAB) {
                const float* wv = &w10t[v * 33];
                float a0 = b10s[v], a1 = a0;
                #pragma unroll
                for (int k4 = 0; k4 < 8; ++k4) {
                    const float4 wk = *(const float4*)(wv + k4 * 4);
                    a0 = fmaf(h0[k4].x, wk.x, a0); a0 = fmaf(h0[k4].y, wk.y, a0);
                    a0 = fmaf(h0[k4].z, wk.z, a0); a0 = fmaf(h0[k4].w, wk.w, a0);
                    a1 = fmaf(h1[k4].x, wk.x, a1); a1 = fmaf(h1[k4].y, wk.y, a1);
                    a1 = fmaf(h1[k4].z, wk.z, a1); a1 = fmaf(h1[k4].w, wk.w, a1);
                }
                val[0][s] = a0; val[1][s] = a1;
            } else {
                val[0][s] = -3.4e38f; val[1][s] = -3.4e38f;
            }
        }

        // top-8 (desc values, lower index wins ties)
        #pragma unroll
        for (int r = 0; r < 2; ++r) {
            const int item = it0 + r;
            const int tt = item >> 12, bb = item & 4095;
            unsigned msk = 0x3Fu;
            for (int sel = 0; sel < 8; ++sel) {
                float bv = -3.4e38f; int bi = 0x7FFFFFFF;
                #pragma unroll
                for (int s = 0; s < 6; ++s) {
                    if (msk & (1u << s)) {
                        const float v2 = val[r][s]; const int i2 = lane + 64 * s;
                        if (v2 > bv || (v2 == bv && i2 < bi)) { bv = v2; bi = i2; }
                    }
                }
                #pragma unroll
                for (int off = 32; off >= 1; off >>= 1) {
                    const float ov = __shfl_xor(bv, off, 64);
                    const int   oi = __shfl_xor(bi, off, 64);
                    if (ov > bv || (ov == bv && oi < bi)) { bv = ov; bi = oi; }
                }
                if ((bi & 63) == lane) msk &= ~(1u << (bi >> 6));
                if (lane == 0) out[(size_t)bb * 192 + tt * 8 + sel] = bi;
            }
        }
    }
}

// ------------------------------------------------------------------
extern "C" void kernel_launch(void* const* d_in, const int* in_sizes, int n_in,
                              void* d_out, int out_size, void* d_ws, size_t ws_size,
                              hipStream_t stream) {
    const float* cin  = (const float*)d_in[0];
    const float* x    = (const float*)d_in[1];
    const float* hid0 = (const float*)d_in[2];
    const float* cel0 = (const float*)d_in[3];
    const float* w1 = (const float*)d_in[4];  const float* b1 = (const float*)d_in[5];
    const float* w2 = (const float*)d_in[6];  const float* b2 = (const float*)d_in[7];
    const float* w3 = (const float*)d_in[8];  const float* b3 = (const float*)d_in[9];
    const float* w4 = (const float*)d_in[10]; const float* b4 = (const float*)d_in[11];
    const float* w5 = (const float*)d_in[12]; const float* b5 = (const float*)d_in[13];
    const float* w6 = (const float*)d_in[14]; const float* b6 = (const float*)d_in[15];
    const float* wih = (const float*)d_in[16]; const float* whh = (const float*)d_in[17];
    const float* bih = (const float*)d_in[18]; const float* bhh = (const float*)d_in[19];
    const float* w10 = (const float*)d_in[20]; const float* b10 = (const float*)d_in[21];

    float* xp  = (float*)d_ws;                        // 4096 x 256
    float* zz  = xp + (size_t)BATCH * 256;            // 4096 x 32
    float* h5s = zz + (size_t)BATCH * 32;             // 24 x 4096 x 32 (12.6 MB)
    int*   out = (int*)d_out;

    k_encoder<<<BATCH, 256, 0, stream>>>(x, w1, b1, w2, b2, xp);
    k_mlp<<<BATCH / 8, 256, 0, stream>>>(cin, xp, w3, b3, w4, b4, w5, b5, w6, b6, zz);
    k_lstm<<<BATCH / 16, 256, 0, stream>>>(zz, hid0, cel0, wih, whh, bih, bhh, h5s);
    k_logits<<<768, 256, 0, stream>>>(h5s, w10, b10, out);
}